// Round 14
// baseline (381.880 us; speedup 1.0000x reference)
//
#include <hip/hip_runtime.h>
#include <cstdint>
#include <cstddef>

#define M_DIM 4096
#define N_DIM 8192
#define K_DIM 4096

typedef __attribute__((ext_vector_type(4))) int int4v;

// ---------------------------------------------------------------------------
// Pack into MFMA-fragment order (int32 -> int8). R3/R8/R13-verified.
// p = 16-row panel, s = 64-byte kstep, lane l: chunk(p,s) is 1024 B where
// lane l holds row 16p+(l&15), k-bytes s*64 + (l>>4)*16 .. +16.
// ---------------------------------------------------------------------------
__global__ void __launch_bounds__(256) pack_frag(const int* __restrict__ a,
                                                 const int* __restrict__ b,
                                                 unsigned char* __restrict__ pa,
                                                 unsigned char* __restrict__ pb) {
    size_t t = (size_t)blockIdx.x * 256 + threadIdx.x;
    const size_t NA = (size_t)(M_DIM / 16) * (K_DIM / 64) * 64;
    const int* __restrict__ src;
    unsigned char* __restrict__ dst;
    if (t < NA) {
        src = a; dst = pa;
    } else {
        src = b; dst = pb; t -= NA;
    }
    const int l = (int)(t & 63);
    const int s = (int)((t >> 6) & 63);
    const int p = (int)(t >> 12);
    const int* g = src + ((size_t)(16 * p + (l & 15))) * K_DIM + s * 64 + (l >> 4) * 16;
    const int4v* g4 = (const int4v*)g;
    int4v o;
#pragma unroll
    for (int q = 0; q < 4; ++q) {
        int4v v = g4[q];
        o[q] = (v[0] & 0xff) | ((v[1] & 0xff) << 8) | ((v[2] & 0xff) << 16) | (v[3] << 24);
    }
    ((int4v*)dst)[t] = o;
}

// ---------------------------------------------------------------------------
// GEMM: block 128(M) x 256(N), 256 thr = 4 waves (R13 geometry), wave tile
// 64x128 (4 A x 8 B panels), mfma_i32_16x16x64_i8, BK=64.
// R14 = R13 with A REMOVED FROM LDS: af fragments are loaded directly from
// the fragment-packed global buffer (1 KB coalesced streams), ping-ponged
// one iter ahead in registers (R5-proven pattern; drained by the existing
// barrier). LDS traffic drops 96->64 KB reads + 24->16 KB writes per CU
// iter-pair — the dominant non-MFMA term in the measured sum-of-pipes.
// B stays LDS-staged (x4 reuse; B-direct would blow the ~19 TB/s cache wall).
// Registers: 128 AGPR acc + ~110 VGPR (bf 32, afp 32, addr) < 256: no spill.
// ---------------------------------------------------------------------------
__device__ inline void async_copy16(const unsigned char* g, unsigned char* l) {
    __builtin_amdgcn_global_load_lds(
        (const __attribute__((address_space(1))) void*)g,
        (__attribute__((address_space(3))) void*)l,
        16, 0, 0);
}

__global__ void __launch_bounds__(256, 2) gemm_i8(const unsigned char* __restrict__ Ap,
                                                  const unsigned char* __restrict__ Bp,
                                                  const _Float16* __restrict__ arow,
                                                  const _Float16* __restrict__ acol,
                                                  _Float16* __restrict__ Cout) {
    __shared__ __align__(16) unsigned char Bs[2 * 16384];  // 16 B-panels x 1 KB, x2

    const int tid  = threadIdx.x;
    const int lane = tid & 63;
    const int wave = tid >> 6;        // 0..3
    const int bn   = blockIdx.x;      // 0..31 (256 cols)
    const int bm   = blockIdx.y;      // 0..31 (128 rows)

    const int pm0 = (wave & 1) * 4;   // A panel base (4 panels = 64 rows)
    const int pn0 = (wave >> 1) * 8;  // B panel base (8 panels = 128 cols)

    // A: direct fragment loads. Wave's panels bm*8 + pm0 + i; per iter T the
    // chunk offset is T*1024; lane offset lane*16.
    const unsigned char* Abase = Ap + (size_t)(bm * 8 + pm0) * 65536 + lane * 16;

    // B staging: wave w stages B panels {4w..4w+3}; 16 KB per iter per block.
    const unsigned char* bg[4];
    int sblo[4];
#pragma unroll
    for (int r = 0; r < 4; ++r) {
        const int p = 4 * wave + r;
        bg[r]   = Bp + (size_t)(bn * 16 + p) * 65536 + lane * 16;
        sblo[r] = p * 1024;  // wave-uniform; HW adds lane*16
    }

    const int b_off = pn0 * 1024 + lane * 16;  // + j*1024

    int4v acc[4][8];
#pragma unroll
    for (int i = 0; i < 4; ++i)
#pragma unroll
        for (int j = 0; j < 8; ++j) acc[i][j] = (int4v)0;

    const int NT = K_DIM / 64;  // 64

    // prologue: A(0) -> register set 0; stage B(0) -> buffer 0
    int4v afp[2][4];
#pragma unroll
    for (int i = 0; i < 4; ++i)
        afp[0][i] = *(const int4v*)(Abase + (size_t)i * 65536);
#pragma unroll
    for (int r = 0; r < 4; ++r) async_copy16(bg[r], Bs + sblo[r]);
    __syncthreads();

#pragma unroll 2
    for (int T = 0; T < NT; ++T) {
        const int cs = T & 1;
        const int cb = cs * 16384;

        if (T + 1 < NT) {
            const size_t gko = (size_t)(T + 1) * 1024;
            // A(T+1) prefetch into the alternate register set (lands under
            // this iter's compute; drained at this iter's barrier)
#pragma unroll
            for (int i = 0; i < 4; ++i)
                afp[cs ^ 1][i] = *(const int4v*)(Abase + (size_t)i * 65536 + gko);
            // B(T+1) staging into the other LDS buffer
#pragma unroll
            for (int r = 0; r < 4; ++r)
                async_copy16(bg[r] + gko, Bs + (cb ^ 16384) + sblo[r]);
        }

        // bulk B fragment reads, compiler-scheduled (R7 lesson: do not pin)
        int4v bf[8];
#pragma unroll
        for (int j = 0; j < 8; ++j)
            bf[j] = *(const int4v*)(Bs + cb + b_off + j * 1024);

#pragma unroll
        for (int i = 0; i < 4; ++i)
#pragma unroll
            for (int j = 0; j < 8; ++j)
                acc[i][j] = __builtin_amdgcn_mfma_i32_16x16x64_i8(afp[cs][i], bf[j],
                                                                  acc[i][j], 0, 0, 0);

        __syncthreads();
    }

    // --- epilogue: C/D layout col=lane&15, row=(lane>>4)*4+reg (verified)
    const int gcol0 = bn * 256 + pn0 * 16 + (lane & 15);
    float ac8[8];
#pragma unroll
    for (int j = 0; j < 8; ++j) ac8[j] = (float)acol[gcol0 + j * 16];

    const size_t grow0 = (size_t)bm * 128 + pm0 * 16 + (lane >> 4) * 4;
#pragma unroll
    for (int i = 0; i < 4; ++i) {
#pragma unroll
        for (int r = 0; r < 4; ++r) {
            const size_t row = grow0 + i * 16 + r;
            const float ar = (float)arow[row];
            _Float16* outp = Cout + row * (size_t)N_DIM + gcol0;
#pragma unroll
            for (int j = 0; j < 8; ++j) {
                float v = (float)acc[i][j][r] * ar * ac8[j];
                outp[j * 16] = (_Float16)v;
            }
        }
    }
}

// ---------------------------------------------------------------------------
extern "C" void kernel_launch(void* const* d_in, const int* in_sizes, int n_in,
                              void* d_out, int out_size, void* d_ws, size_t ws_size,
                              hipStream_t stream) {
    const int* a = (const int*)d_in[0];             // [M,K] int32 (int8 values)
    const int* b = (const int*)d_in[1];             // [N,K] int32 (int8 values)
    const _Float16* ar = (const _Float16*)d_in[2];  // [M] fp16
    const _Float16* ac = (const _Float16*)d_in[3];  // [N] fp16
    _Float16* out = (_Float16*)d_out;               // [M,N] fp16

    unsigned char* pa = (unsigned char*)d_ws;        // 16 MB
    unsigned char* pb = pa + (size_t)M_DIM * K_DIM;  // 32 MB

    const size_t total_frag = (size_t)(M_DIM / 16 + N_DIM / 16) * (K_DIM / 64) * 64;
    pack_frag<<<(int)(total_frag / 256), 256, 0, stream>>>(a, b, pa, pb);

    dim3 grid(N_DIM / 256, M_DIM / 128);
    gemm_i8<<<grid, 256, 0, stream>>>(pa, pb, ar, ac, out);
}

// Round 15
// 373.238 us; speedup vs baseline: 1.0232x; 1.0232x over previous
//
#include <hip/hip_runtime.h>
#include <cstdint>
#include <cstddef>

#define M_DIM 4096
#define N_DIM 8192
#define K_DIM 4096

typedef __attribute__((ext_vector_type(4))) int int4v;

// ---------------------------------------------------------------------------
// Pack into MFMA-fragment order (int32 -> int8). R3/R8-verified, identical.
// p = 16-row panel, s = 64-byte kstep, lane l: chunk(p,s) is 1024 B where
// lane l holds row 16p+(l&15), k-bytes s*64 + (l>>4)*16 .. +16.
// ---------------------------------------------------------------------------
__global__ void __launch_bounds__(256) pack_frag(const int* __restrict__ a,
                                                 const int* __restrict__ b,
                                                 unsigned char* __restrict__ pa,
                                                 unsigned char* __restrict__ pb) {
    size_t t = (size_t)blockIdx.x * 256 + threadIdx.x;
    const size_t NA = (size_t)(M_DIM / 16) * (K_DIM / 64) * 64;
    const int* __restrict__ src;
    unsigned char* __restrict__ dst;
    if (t < NA) {
        src = a; dst = pa;
    } else {
        src = b; dst = pb; t -= NA;
    }
    const int l = (int)(t & 63);
    const int s = (int)((t >> 6) & 63);
    const int p = (int)(t >> 12);
    const int* g = src + ((size_t)(16 * p + (l & 15))) * K_DIM + s * 64 + (l >> 4) * 16;
    const int4v* g4 = (const int4v*)g;
    int4v o;
#pragma unroll
    for (int q = 0; q < 4; ++q) {
        int4v v = g4[q];
        o[q] = (v[0] & 0xff) | ((v[1] & 0xff) << 8) | ((v[2] & 0xff) << 16) | (v[3] << 24);
    }
    ((int4v*)dst)[t] = o;
}

// ---------------------------------------------------------------------------
// GEMM: block 256x256, 512 thr = 8 waves (2/SIMD), wave tile 64x128
// (4 A x 8 B panels), mfma_i32_16x16x64_i8 (verified layouts), BK=64.
// Quad-buffered LDS (4 x 32 KB), staging 2 iters ahead, barrier per 2 iters
// — byte-identical to R8 except:
// FORCED ANTI-PHASE: within each barrier window, waves 0-3 process iters
// (T, T+1) while waves 4-7 (their SIMD mates, since wave i -> SIMD i%4)
// process (T+1, T). Both buffers are valid at window entry (staged two
// windows ahead), so read order is free, and integer accumulation over K
// commutes exactly. At any instant half the CU's waves are in the LDS-read
// phase and half in the MFMA phase -> the per-CU LDS pipe (~1500 cy/iter,
// dominant) overlaps the per-SIMD matrix pipes (~650 cy/iter) instead of
// running in sum (the phase-lock that held R6/R8/R12/R13 at ~2470 cy/iter).
// ---------------------------------------------------------------------------
__device__ inline void async_copy16(const unsigned char* g, unsigned char* l) {
    __builtin_amdgcn_global_load_lds(
        (const __attribute__((address_space(1))) void*)g,
        (__attribute__((address_space(3))) void*)l,
        16, 0, 0);
}

__global__ void __launch_bounds__(512, 2) gemm_i8(const unsigned char* __restrict__ Ap,
                                                  const unsigned char* __restrict__ Bp,
                                                  const _Float16* __restrict__ arow,
                                                  const _Float16* __restrict__ acol,
                                                  _Float16* __restrict__ Cout) {
    __shared__ __align__(16) unsigned char As[4 * 16384];
    __shared__ __align__(16) unsigned char Bs[4 * 16384];

    const int tid  = threadIdx.x;
    const int lane = tid & 63;
    const int wave = tid >> 6;        // 0..7
    const int bn   = blockIdx.x;      // 0..31 (256 cols)
    const int bm   = blockIdx.y;      // 0..15 (256 rows)

    const int pm0 = (wave & 3) * 4;   // A panel base (4 panels = 64 rows)
    const int pn0 = (wave >> 2) * 8;  // B panel base (8 panels = 128 cols)
    const int ph  = (wave >> 2) & 1;  // SIMD-mates (w, w+4) -> opposite phase

    // staging: wave w stages A panels {2w,2w+1} and B panels {2w,2w+1}
    const unsigned char* ag[2];
    const unsigned char* bg[2];
    int slo[2];
#pragma unroll
    for (int r = 0; r < 2; ++r) {
        const int p = 2 * wave + r;
        ag[r]  = Ap + (size_t)(bm * 16 + p) * 65536 + lane * 16;
        bg[r]  = Bp + (size_t)(bn * 16 + p) * 65536 + lane * 16;
        slo[r] = p * 1024;  // wave-uniform; HW adds lane*16
    }

    const int a_off = pm0 * 1024 + lane * 16;  // + i*1024
    const int b_off = pn0 * 1024 + lane * 16;  // + j*1024

    int4v acc[4][8];
#pragma unroll
    for (int i = 0; i < 4; ++i)
#pragma unroll
        for (int j = 0; j < 8; ++j) acc[i][j] = (int4v)0;

    const int NT = K_DIM / 64;  // 64, even

    // prologue: stage T=0 -> buf0, T=1 -> buf1
#pragma unroll
    for (int r = 0; r < 2; ++r) {
        async_copy16(ag[r], As + slo[r]);
        async_copy16(bg[r], Bs + slo[r]);
        async_copy16(ag[r] + 1024, As + 16384 + slo[r]);
        async_copy16(bg[r] + 1024, Bs + 16384 + slo[r]);
    }
    __syncthreads();

    for (int T = 0; T < NT; T += 2) {
        // stage T+2, T+3 into their ring buffers (drained at the barrier
        // below, after TWO full compute iterations)
        if (T + 2 < NT) {
            const size_t gko = (size_t)(T + 2) * 1024;
            const int buf = ((T + 2) & 3) * 16384;
#pragma unroll
            for (int r = 0; r < 2; ++r) {
                async_copy16(ag[r] + gko, As + buf + slo[r]);
                async_copy16(bg[r] + gko, Bs + buf + slo[r]);
            }
            const size_t gko3 = gko + 1024;
            const int buf3 = ((T + 3) & 3) * 16384;
#pragma unroll
            for (int r = 0; r < 2; ++r) {
                async_copy16(ag[r] + gko3, As + buf3 + slo[r]);
                async_copy16(bg[r] + gko3, Bs + buf3 + slo[r]);
            }
        }

        // two compute iterations, order phase-flipped per SIMD-mate pair
#pragma unroll
        for (int u = 0; u < 2; ++u) {
            const int v = u ^ ph;
            const int cur = ((T + v) & 3) * 16384;
            const unsigned char* Ac = As + cur;
            const unsigned char* Bc = Bs + cur;

            int4v af[4], bf[8];
#pragma unroll
            for (int i = 0; i < 4; ++i)
                af[i] = *(const int4v*)(Ac + a_off + i * 1024);
#pragma unroll
            for (int j = 0; j < 8; ++j)
                bf[j] = *(const int4v*)(Bc + b_off + j * 1024);

#pragma unroll
            for (int i = 0; i < 4; ++i)
#pragma unroll
                for (int j = 0; j < 8; ++j)
                    acc[i][j] = __builtin_amdgcn_mfma_i32_16x16x64_i8(af[i], bf[j],
                                                                      acc[i][j], 0, 0, 0);
        }

        __syncthreads();
    }

    // --- epilogue: C/D layout col=lane&15, row=(lane>>4)*4+reg (verified)
    const int gcol0 = bn * 256 + pn0 * 16 + (lane & 15);
    float ac8[8];
#pragma unroll
    for (int j = 0; j < 8; ++j) ac8[j] = (float)acol[gcol0 + j * 16];

    const size_t grow0 = (size_t)bm * 256 + pm0 * 16 + (lane >> 4) * 4;
#pragma unroll
    for (int i = 0; i < 4; ++i) {
#pragma unroll
        for (int r = 0; r < 4; ++r) {
            const size_t row = grow0 + i * 16 + r;
            const float ar = (float)arow[row];
            _Float16* outp = Cout + row * (size_t)N_DIM + gcol0;
#pragma unroll
            for (int j = 0; j < 8; ++j) {
                float v = (float)acc[i][j][r] * ar * ac8[j];
                outp[j * 16] = (_Float16)v;
            }
        }
    }
}

// ---------------------------------------------------------------------------
extern "C" void kernel_launch(void* const* d_in, const int* in_sizes, int n_in,
                              void* d_out, int out_size, void* d_ws, size_t ws_size,
                              hipStream_t stream) {
    const int* a = (const int*)d_in[0];             // [M,K] int32 (int8 values)
    const int* b = (const int*)d_in[1];             // [N,K] int32 (int8 values)
    const _Float16* ar = (const _Float16*)d_in[2];  // [M] fp16
    const _Float16* ac = (const _Float16*)d_in[3];  // [N] fp16
    _Float16* out = (_Float16*)d_out;               // [M,N] fp16

    unsigned char* pa = (unsigned char*)d_ws;        // 16 MB
    unsigned char* pb = pa + (size_t)M_DIM * K_DIM;  // 32 MB

    const size_t total_frag = (size_t)(M_DIM / 16 + N_DIM / 16) * (K_DIM / 64) * 64;
    pack_frag<<<(int)(total_frag / 256), 256, 0, stream>>>(a, b, pa, pb);

    dim3 grid(N_DIM / 256, M_DIM / 256);
    gemm_i8<<<grid, 512, 0, stream>>>(pa, pb, ar, ac, out);
}